// Round 13
// baseline (250.702 us; speedup 1.0000x reference)
//
#include <hip/hip_runtime.h>
#include <math.h>

#define NN 100000      // nodes
#define DD 64          // dim
#define NE 1200000     // edges (without self-loops)
#define NB 391         // buckets of 256 nodes
#define SCH 2048       // edges per scatter block
#define SCB ((NE + SCH - 1) / SCH)   // 586 scatter blocks
#define BCAP 4096      // per-bucket ebuf capacity (mean 3072, sigma 55 -> 18-sigma margin)
#define CCAP (BCAP + 256)   // per-bucket csr capacity (edges + self-loops)
#define GB ((NN + 63) / 64) // 1563 row tiles for GEMM
#define HS 88          // LDS row stride in shorts (176B: 16B-aligned, <=2-way banks)

typedef __attribute__((ext_vector_type(8))) short bf16x8;
typedef __attribute__((ext_vector_type(4))) float f32x4;
typedef __attribute__((ext_vector_type(2))) float f32x2;

#if __has_builtin(__builtin_amdgcn_exp2f)
#define EXP2(x) __builtin_amdgcn_exp2f(x)
#else
#define EXP2(x) exp2f(x)
#endif

__device__ __forceinline__ unsigned short f2bf(float x) {
    unsigned u = __float_as_uint(x);
    return (unsigned short)((u + 0x7FFFu + ((u >> 16) & 1u)) >> 16);   // RNE
}
__device__ __forceinline__ float bf2f(unsigned short b) {
    return __uint_as_float(((unsigned)b) << 16);
}

__device__ __forceinline__ float gelu_exact(float x) {
    return 0.5f * x * (1.0f + erff(x * 0.70710678118654752f));
}

// sum across each 16-lane row via DPP row_ror 1/2/4/8 (pure VALU, no DS)
__device__ __forceinline__ float row16_sum(float x) {
    int t;
    t = __builtin_amdgcn_update_dpp(0, __float_as_int(x), 0x121, 0xf, 0xf, true);
    x += __int_as_float(t);
    t = __builtin_amdgcn_update_dpp(0, __float_as_int(x), 0x122, 0xf, 0xf, true);
    x += __int_as_float(t);
    t = __builtin_amdgcn_update_dpp(0, __float_as_int(x), 0x124, 0xf, 0xf, true);
    x += __int_as_float(t);
    t = __builtin_amdgcn_update_dpp(0, __float_as_int(x), 0x128, 0xf, 0xf, true);
    x += __int_as_float(t);
    return x;
}

// ---------------- weight precompute body (runs in 3 trailing blocks of k_bsw) ----------------
__device__ __forceinline__ void wall_body(
    int blk, int tid,
    const float* __restrict__ Wl, const float* __restrict__ Wr,
    const float* __restrict__ g, const float* __restrict__ be,
    const float* __restrict__ pw, const float* __restrict__ pb,
    unsigned short* __restrict__ aT0, unsigned short* __restrict__ aT1,
    unsigned short* __restrict__ fT,
    float* __restrict__ S0, float* __restrict__ C0,
    float* __restrict__ S1, float* __restrict__ C1, float* __restrict__ Cf)
{
    if (blk < 2) {
        if (tid >= 128) return;
        const int c = tid;
        const float* WL = Wl + blk * DD * DD;
        const float* WR = Wr + blk * DD * DD;
        const float* gg = g + blk * DD;
        const float* bb = be + blk * DD;
        unsigned short* aT = blk ? aT1 : aT0;
        float* S = blk ? S1 : S0;
        float* C = blk ? C1 : C0;
        const float* W = (c < 64) ? WL : WR;
        const int cc = c & 63;
        float s = 0.f, cC = 0.f;
        unsigned short* hi_p = aT + c * 64;
        unsigned short* lo_p = aT + 128 * 64 + c * 64;
        #pragma unroll 8
        for (int k = 0; k < 64; ++k) {
            float w = W[k * 64 + cc];
            float a = gg[k] * w;
            unsigned short hi = f2bf(a);
            unsigned short lo = f2bf(a - bf2f(hi));
            hi_p[k] = hi; lo_p[k] = lo;
            s += a;
            cC = fmaf(bb[k], w, cC);
        }
        S[c] = s; C[c] = cC;
    } else {
        if (tid >= 64) return;
        const int c = tid;
        unsigned short* hi_p = fT + c * 64;
        unsigned short* lo_p = fT + 64 * 64 + c * 64;
        #pragma unroll 8
        for (int k = 0; k < 64; ++k) {
            float w = pw[k * 64 + c];
            unsigned short hi = f2bf(w);
            unsigned short lo = f2bf(w - bf2f(hi));
            hi_p[k] = hi; lo_p[k] = lo;
        }
        Cf[c] = pb[c];
    }
}

// ---------------- fused: bucket scatter (blocks < SCB) || weight precompute (3 blocks) ----------------
// bkcnt[b] counts edges in bucket b (zeroed by hipMemsetAsync before launch).
__global__ __launch_bounds__(256) void k_bsw(
    const int* __restrict__ src, const int* __restrict__ tgt,
    int* __restrict__ bkcnt, unsigned int* __restrict__ ebuf,
    const float* __restrict__ Wl, const float* __restrict__ Wr,
    const float* __restrict__ g, const float* __restrict__ be,
    const float* __restrict__ pw, const float* __restrict__ pb,
    unsigned short* __restrict__ aT0, unsigned short* __restrict__ aT1,
    unsigned short* __restrict__ fT,
    float* __restrict__ S0, float* __restrict__ C0,
    float* __restrict__ S1, float* __restrict__ C1, float* __restrict__ Cf)
{
    __shared__ int stgt[SCH];
    __shared__ unsigned short srk[SCH];
    __shared__ int hist[NB];
    __shared__ int hbase[NB];
    if (blockIdx.x >= SCB) {
        wall_body(blockIdx.x - SCB, threadIdx.x, Wl, Wr, g, be, pw, pb,
                  aT0, aT1, fT, S0, C0, S1, C1, Cf);
        return;
    }
    const int base = blockIdx.x * SCH;
    const int cnt = min(SCH, NE - base);
    const int tid = threadIdx.x;
    for (int i = tid; i < NB; i += 256) hist[i] = 0;
    for (int i = tid; i < cnt; i += 256) stgt[i] = tgt[base + i];
    __syncthreads();
    for (int i = tid; i < cnt; i += 256)
        srk[i] = (unsigned short)atomicAdd(&hist[stgt[i] >> 8], 1);
    __syncthreads();
    for (int b = tid; b < NB; b += 256) {
        int c = hist[b];
        hbase[b] = c ? (b * BCAP + atomicAdd(&bkcnt[b], c)) : 0;
    }
    __syncthreads();
    for (int i = tid; i < cnt; i += 256) {
        int t = stgt[i];
        unsigned int e = ((unsigned int)src[base + i] << 8) | (unsigned int)(t & 255);
        ebuf[hbase[t >> 8] + (int)srk[i]] = e;
    }
}

// ---------------- MFMA node GEMM tile (device body) ----------------
template<int CTW, bool LN>
__device__ __forceinline__ void gemm_tile(
    const int tile, unsigned short* hbh, unsigned short* hbl,
    float* smean, float* srho,
    const float* __restrict__ h, const unsigned short* __restrict__ aT,
    const float* __restrict__ S, const float* __restrict__ C,
    unsigned short* __restrict__ xlb, unsigned short* __restrict__ xrb,
    float* __restrict__ outp)
{
    const int tid = threadIdx.x;
    {
        const int row = tid >> 2, q = tid & 3;
        const int node = min(tile + row, NN - 1);
        const float* hp = h + (size_t)node * DD + q * 16;
        float4 v[4];
        #pragma unroll
        for (int i = 0; i < 4; ++i) v[i] = *(const float4*)(hp + i * 4);
        if (LN) {
            float sum = 0.f, ssq = 0.f;
            #pragma unroll
            for (int i = 0; i < 4; ++i) {
                sum += v[i].x + v[i].y + v[i].z + v[i].w;
                ssq += v[i].x * v[i].x + v[i].y * v[i].y + v[i].z * v[i].z + v[i].w * v[i].w;
            }
            sum += __shfl_xor(sum, 1, 64); ssq += __shfl_xor(ssq, 1, 64);
            sum += __shfl_xor(sum, 2, 64); ssq += __shfl_xor(ssq, 2, 64);
            if (q == 0) {
                float mean = sum * 0.015625f;
                float var = ssq * 0.015625f - mean * mean;
                smean[row] = mean;
                srho[row] = rsqrtf(var + 1e-5f);
            }
        }
        #pragma unroll
        for (int half = 0; half < 2; ++half) {
            bf16x8 ph, pl;
            #pragma unroll
            for (int e = 0; e < 8; ++e) {
                float f = (&v[half * 2 + (e >> 2)].x)[e & 3];
                unsigned short hi = f2bf(f);
                unsigned short lo = f2bf(f - bf2f(hi));
                ph[e] = (short)hi; pl[e] = (short)lo;
            }
            const int so = row * HS + q * 16 + half * 8;
            *(bf16x8*)&hbh[so] = ph;
            *(bf16x8*)&hbl[so] = pl;
        }
    }
    __syncthreads();
    const int lane = tid & 63;
    const int wslot = tid >> 6;
    const int li16 = lane & 15;
    const int g16 = lane >> 4;
    const int NCT = CTW * 4;
    f32x4 acc[CTW][4];
    #pragma unroll
    for (int c = 0; c < CTW; ++c)
        #pragma unroll
        for (int rt = 0; rt < 4; ++rt) acc[c][rt] = (f32x4){0.f, 0.f, 0.f, 0.f};
    #pragma unroll
    for (int kk = 0; kk < 2; ++kk) {
        bf16x8 ah[4], al[4];
        #pragma unroll
        for (int rt = 0; rt < 4; ++rt) {
            const int so = (rt * 16 + li16) * HS + kk * 32 + g16 * 8;
            ah[rt] = *(const bf16x8*)&hbh[so];
            al[rt] = *(const bf16x8*)&hbl[so];
        }
        #pragma unroll
        for (int c = 0; c < CTW; ++c) {
            const int ct = wslot + c * 4;
            const unsigned short* bp = aT + (ct * 16 + li16) * 64 + kk * 32 + g16 * 8;
            bf16x8 bh = *(const bf16x8*)bp;
            bf16x8 bl = *(const bf16x8*)(bp + NCT * 16 * 64);
            #pragma unroll
            for (int rt = 0; rt < 4; ++rt) {
                acc[c][rt] = __builtin_amdgcn_mfma_f32_16x16x32_bf16(ah[rt], bh, acc[c][rt], 0, 0, 0);
                acc[c][rt] = __builtin_amdgcn_mfma_f32_16x16x32_bf16(al[rt], bh, acc[c][rt], 0, 0, 0);
                acc[c][rt] = __builtin_amdgcn_mfma_f32_16x16x32_bf16(ah[rt], bl, acc[c][rt], 0, 0, 0);
            }
        }
    }
    #pragma unroll
    for (int c = 0; c < CTW; ++c) {
        const int ct = wslot + c * 4;
        const int col = ct * 16 + li16;
        const float Cc = C[col];
        float Sc = 0.f;
        if (LN) Sc = S[col];
        #pragma unroll
        for (int rt = 0; rt < 4; ++rt) {
            const int r0 = rt * 16 + g16 * 4;
            #pragma unroll
            for (int j = 0; j < 4; ++j) {
                const int row2 = r0 + j;
                const int node = tile + row2;
                if (node < NN) {
                    float p = acc[c][rt][j];
                    if (LN) {
                        float val = fmaf(srho[row2], p - smean[row2] * Sc, Cc);
                        unsigned short* xb = (ct < 4) ? xlb : xrb;
                        xb[(size_t)node * DD + (col & 63)] = f2bf(val);
                    } else {
                        outp[(size_t)node * DD + col] = p + Cc;
                    }
                }
            }
        }
    }
}

template<int CTW, bool LN>
__global__ __launch_bounds__(256) void k_gemm(
    const float* __restrict__ h, const unsigned short* __restrict__ aT,
    const float* __restrict__ S, const float* __restrict__ C,
    unsigned short* __restrict__ xlb, unsigned short* __restrict__ xrb,
    float* __restrict__ outp)
{
    __shared__ __align__(16) unsigned short hbh[64 * HS];
    __shared__ __align__(16) unsigned short hbl[64 * HS];
    __shared__ float smean[64], srho[64];
    gemm_tile<CTW, LN>(blockIdx.x * 64, hbh, hbl, smean, srho,
                       h, aT, S, C, xlb, xrb, outp);
}

// ---------------- fused: bucket-finalize (blocks < NB) || layer-0 GEMM (rest) ----------------
__global__ __launch_bounds__(256) void k_bfg(
    const int* __restrict__ bkcnt, const unsigned int* __restrict__ ebuf,
    int2* __restrict__ rowse, int* __restrict__ csr,
    const float* __restrict__ h, const unsigned short* __restrict__ aT,
    const float* __restrict__ S, const float* __restrict__ C,
    unsigned short* __restrict__ xlb, unsigned short* __restrict__ xrb)
{
    __shared__ __align__(16) unsigned short hbh[64 * HS];
    __shared__ __align__(16) unsigned short hbl[64 * HS];
    __shared__ float smean[64], srho[64];
    __shared__ int hist[256];
    __shared__ int pos[256];
    __shared__ int wsum[4];
    if (blockIdx.x < NB) {
        const int b = blockIdx.x, tid = threadIdx.x;
        const int bb = b * BCAP;
        const int be = bb + bkcnt[b];
        hist[tid] = 0;
        __syncthreads();
        for (int i = bb + tid; i < be; i += 256) atomicAdd(&hist[ebuf[i] & 255u], 1);
        __syncthreads();
        const int v = hist[tid];
        const int lane = tid & 63, w = tid >> 6;
        int sc = v;
        #pragma unroll
        for (int o = 1; o < 64; o <<= 1) { int t = __shfl_up(sc, o, 64); if (lane >= o) sc += t; }
        if (lane == 63) wsum[w] = sc;
        __syncthreads();
        int off = 0;
        for (int k = 0; k < w; ++k) off += wsum[k];
        const int node = b * 256 + tid;
        const int rp = b * CCAP + off + sc - v + tid;   // +tid: self slots of preceding nodes
        if (node < NN) {
            rowse[node] = make_int2(rp, rp + 1 + v);    // [beg, end): self + deg edges
            csr[rp] = node << 6;                        // self-loop first (pre-scaled by DD)
        }
        pos[tid] = rp + 1;
        __syncthreads();
        for (int i = bb + tid; i < be; i += 256) {
            unsigned int e = ebuf[i];
            int p = atomicAdd(&pos[e & 255u], 1);
            csr[p] = (int)(e >> 8) << 6;                // pre-scaled by DD
        }
    } else {
        gemm_tile<2, true>((blockIdx.x - NB) * 64, hbh, hbl, smean, srho,
                           h, aT, S, C, xlb, xrb, nullptr);
    }
}

// ---------------- aggregation: one wave per TWO target nodes, 16 lanes x 4 edges each ----------------
// bf16 gathers, predicated 2-deep pipelines (x2 nodes), DPP reduce, packed math, distributed epilogue.
__global__ __launch_bounds__(256) void k_agg(
    const int2* __restrict__ rowse, const int* __restrict__ csr,
    const unsigned short* __restrict__ xlb, const unsigned short* __restrict__ xrb,
    const float* __restrict__ att, const float* __restrict__ cbias,
    const float* __restrict__ h_in, float* __restrict__ h_out)
{
    const int lane = threadIdx.x & 63;
    const int li   = lane & 15;     // feature-quad index
    const int sub  = lane >> 4;     // edge slot 0..3
    const int li4  = li * 4;
    const int fidx = li4 + sub;     // feature this lane owns in the epilogue
    const int wid  = (blockIdx.x * 256 + threadIdx.x) >> 6;
    const int W    = gridDim.x * 4;
    const float L2E = 1.4426950408889634f;
    const float4 ar = *(const float4*)&att[li4];
    const f32x2 a1_01  = {L2E * ar.x, L2E * ar.y};
    const f32x2 a1_23  = {L2E * ar.z, L2E * ar.w};
    const f32x2 a02_01 = {0.2f * L2E * ar.x, 0.2f * L2E * ar.y};
    const f32x2 a02_23 = {0.2f * L2E * ar.z, 0.2f * L2E * ar.w};
    const float cb = cbias[fidx];
    const f32x2 z2 = {0.f, 0.f};

#define LOAD_XR(nS, xr01S, xr23S) { \
    const uint2 xru = *(const uint2*)&xrb[(size_t)(nS) * DD + li4]; \
    xr01S.x = __uint_as_float(xru.x << 16); \
    xr01S.y = __uint_as_float(xru.x & 0xFFFF0000u); \
    xr23S.x = __uint_as_float(xru.y << 16); \
    xr23S.y = __uint_as_float(xru.y & 0xFFFF0000u); }

#define CHUNK_STEP(j0S, j1S, v0S, v1S, endS, end1S, denS, acc01S, acc23S, xr01S, xr23S) { \
    const uint2 cur = v0S; const int jc = j0S; \
    v0S = v1S; j0S = j1S; j1S += 4; \
    if (j1S <= end1S) v1S = *(const uint2*)&xlb[(unsigned)csr[j1S] + li4]; \
    f32x2 f01, f23; \
    f01.x = __uint_as_float(cur.x << 16); \
    f01.y = __uint_as_float(cur.x & 0xFFFF0000u); \
    f23.x = __uint_as_float(cur.y << 16); \
    f23.y = __uint_as_float(cur.y & 0xFFFF0000u); \
    const f32x2 t01 = f01 + xr01S; \
    const f32x2 t23 = f23 + xr23S; \
    f32x2 pv = __builtin_elementwise_max(t01, z2) * a1_01; \
    pv = __builtin_elementwise_min(t01, z2) * a02_01 + pv; \
    pv = __builtin_elementwise_max(t23, z2) * a1_23 + pv; \
    pv = __builtin_elementwise_min(t23, z2) * a02_23 + pv; \
    float p = row16_sum(pv.x + pv.y); \
    float ex = (jc < endS) ? EXP2(p) : 0.f; \
    denS += ex; \
    const f32x2 ex2 = {ex, ex}; \
    acc01S = f01 * ex2 + acc01S; \
    acc23S = f23 * ex2 + acc23S; }

    for (int nA = wid; nA < NN; nA += 2 * W) {
        const int nB = nA + W;
        const bool vB = nB < NN;
        f32x2 xr01A, xr23A, xr01B, xr23B;
        LOAD_XR(nA, xr01A, xr23A);
        LOAD_XR(vB ? nB : nA, xr01B, xr23B);
        const int2 seA = rowse[nA];
        const int2 seB = rowse[vB ? nB : nA];
        const int begA = seA.x, endA = seA.y;
        const int begB = seB.x, endB = vB ? seB.y : seB.x;   // empty if invalid
        const int end1A = endA - 1, end1B = endB - 1;
        int j0A = begA + sub, j1A = j0A + 4;
        int j0B = begB + sub, j1B = j0B + 4;
        uint2 v0A = {0u, 0u}, v1A = {0u, 0u}, v0B = {0u, 0u}, v1B = {0u, 0u};
        if (j0A <= end1A) v0A = *(const uint2*)&xlb[(unsigned)csr[j0A] + li4];
        if (j0B <= end1B) v0B = *(const uint2*)&xlb[(unsigned)csr[j0B] + li4];
        if (j1A <= end1A) v1A = *(const uint2*)&xlb[(unsigned)csr[j1A] + li4];
        if (j1B <= end1B) v1B = *(const uint2*)&xlb[(unsigned)csr[j1B] + li4];
        float denA = 0.f, denB = 0.f;
        f32x2 acc01A = z2, acc23A = z2, acc01B = z2, acc23B = z2;
        const int nchA = (endA - begA + 3) >> 2;
        const int nchB = (endB - begB + 3) >> 2;
        const int nchM = max(nchA, nchB);
        for (int c = 0; c < nchM; ++c) {
            CHUNK_STEP(j0A, j1A, v0A, v1A, endA, end1A, denA, acc01A, acc23A, xr01A, xr23A);
            CHUNK_STEP(j0B, j1B, v0B, v1B, endB, end1B, denB, acc01B, acc23B, xr01B, xr23B);
        }
        // full butterfly across the 4 edge slots: all lanes get totals
        #pragma unroll
        for (int o = 16; o < 64; o <<= 1) {
            acc01A.x += __shfl_xor(acc01A.x, o, 64);
            acc01A.y += __shfl_xor(acc01A.y, o, 64);
            acc23A.x += __shfl_xor(acc23A.x, o, 64);
            acc23A.y += __shfl_xor(acc23A.y, o, 64);
            denA     += __shfl_xor(denA,     o, 64);
            acc01B.x += __shfl_xor(acc01B.x, o, 64);
            acc01B.y += __shfl_xor(acc01B.y, o, 64);
            acc23B.x += __shfl_xor(acc23B.x, o, 64);
            acc23B.y += __shfl_xor(acc23B.y, o, 64);
            denB     += __shfl_xor(denB,     o, 64);
        }
        // distributed epilogue: each lane finishes ONE feature per node
        {
            const float id = 1.f / (denA + 1e-16f);
            const float w01 = (sub & 1) ? acc01A.y : acc01A.x;
            const float w23 = (sub & 1) ? acc23A.y : acc23A.x;
            const float val = (sub & 2) ? w23 : w01;
            const float o = gelu_exact(fmaf(val, id, cb)) + h_in[(size_t)nA * DD + fidx];
            h_out[(size_t)nA * DD + fidx] = o;
        }
        if (vB) {
            const float id = 1.f / (denB + 1e-16f);
            const float w01 = (sub & 1) ? acc01B.y : acc01B.x;
            const float w23 = (sub & 1) ? acc23B.y : acc23B.x;
            const float val = (sub & 2) ? w23 : w01;
            const float o = gelu_exact(fmaf(val, id, cb)) + h_in[(size_t)nB * DD + fidx];
            h_out[(size_t)nB * DD + fidx] = o;
        }
    }
#undef CHUNK_STEP
#undef LOAD_XR
}

extern "C" void kernel_launch(void* const* d_in, const int* in_sizes, int n_in,
                              void* d_out, int out_size, void* d_ws, size_t ws_size,
                              hipStream_t stream) {
    const int*   edge_index = (const int*)d_in[1];
    const int*   src   = edge_index;
    const int*   tgt   = edge_index + NE;
    const float* emb   = (const float*)d_in[2];
    const float* ln_g  = (const float*)d_in[3];
    const float* ln_b  = (const float*)d_in[4];
    const float* Wl    = (const float*)d_in[5];
    const float* Wr    = (const float*)d_in[6];
    const float* att   = (const float*)d_in[7];
    const float* cbias = (const float*)d_in[8];
    const float* pw    = (const float*)d_in[9];
    const float* pb    = (const float*)d_in[10];
    float* out = (float*)d_out;

    unsigned short* xlb = (unsigned short*)d_ws;             // NN*64 bf16
    unsigned short* xrb = xlb + (size_t)NN * DD;             // NN*64 bf16
    int* csr            = (int*)(xrb + (size_t)NN * DD);     // NB*CCAP
    unsigned int* ebuf  = (unsigned int*)(csr + NB * CCAP);  // NB*BCAP
    int2* rowse         = (int2*)(ebuf + (size_t)NB * BCAP); // NN int2
    int* bkcnt          = (int*)(rowse + NN);                // 400 (padded)
    unsigned short* aT0 = (unsigned short*)(bkcnt + 400);    // 2*128*64
    unsigned short* aT1 = aT0 + 2 * 128 * 64;
    unsigned short* fT  = aT1 + 2 * 128 * 64;                // 2*64*64
    float* S0 = (float*)(fT + 2 * 64 * 64);
    float* C0 = S0 + 128;
    float* S1 = C0 + 128;
    float* C1 = S1 + 128;
    float* Cf = C1 + 128;

    const int AGG_BLOCKS = 2048;

    // D0: zero bucket counters (DMA, no kernel)
    hipMemsetAsync(bkcnt, 0, NB * sizeof(int), stream);

    // D1: bucket scatter || weight precompute (fused)
    k_bsw<<<SCB + 3, 256, 0, stream>>>(src, tgt, bkcnt, ebuf,
                                       Wl, Wr, ln_g, ln_b, pw, pb,
                                       aT0, aT1, fT, S0, C0, S1, C1, Cf);

    // D2: bucket finalize (CSR+rowse) || layer-0 GEMM, fused
    k_bfg<<<NB + GB, 256, 0, stream>>>(bkcnt, ebuf, rowse, csr,
                                       emb, aT0, S0, C0, xlb, xrb);

    // D3: layer-0 aggregation -> h1 (out)
    k_agg<<<AGG_BLOCKS, 256, 0, stream>>>(rowse, csr, xlb, xrb, att, cbias, emb, out);

    // D4: layer-1 GEMM (h1 -> xlb, xrb)
    k_gemm<2, true><<<GB, 256, 0, stream>>>(out, aT1, S1, C1, xlb, xrb, nullptr);

    // D5: layer-1 aggregation -> h2 (out)
    k_agg<<<AGG_BLOCKS, 256, 0, stream>>>(rowse, csr, xlb, xrb, att + DD, cbias + DD, out, out);

    // D6: final projection (MFMA, in-place per row tile)
    k_gemm<1, false><<<GB, 256, 0, stream>>>(out, fT, nullptr, Cf, nullptr, nullptr, out);
}

// Round 14
// 220.484 us; speedup vs baseline: 1.1371x; 1.1371x over previous
//
#include <hip/hip_runtime.h>
#include <math.h>

#define NN 100000      // nodes
#define DD 64          // dim
#define NE 1200000     // edges (without self-loops)
#define NB 391         // buckets of 256 nodes
#define SCH 2048       // edges per scatter block
#define SCB ((NE + SCH - 1) / SCH)   // 586 scatter blocks
#define BCAP 4096      // per-bucket ebuf capacity (mean 3072, sigma 55 -> 18-sigma margin)
#define CCAP (BCAP + 256)   // per-bucket csr capacity (edges + self-loops)
#define GB ((NN + 63) / 64) // 1563 row tiles for GEMM
#define HS 88          // LDS row stride in shorts (176B: 16B-aligned, <=2-way banks)

typedef __attribute__((ext_vector_type(8))) short bf16x8;
typedef __attribute__((ext_vector_type(4))) float f32x4;
typedef __attribute__((ext_vector_type(2))) float f32x2;

#if __has_builtin(__builtin_amdgcn_exp2f)
#define EXP2(x) __builtin_amdgcn_exp2f(x)
#else
#define EXP2(x) exp2f(x)
#endif

__device__ __forceinline__ unsigned short f2bf(float x) {
    unsigned u = __float_as_uint(x);
    return (unsigned short)((u + 0x7FFFu + ((u >> 16) & 1u)) >> 16);   // RNE
}
__device__ __forceinline__ float bf2f(unsigned short b) {
    return __uint_as_float(((unsigned)b) << 16);
}

__device__ __forceinline__ float gelu_exact(float x) {
    return 0.5f * x * (1.0f + erff(x * 0.70710678118654752f));
}

// sum across each 16-lane row via DPP row_ror 1/2/4/8 (pure VALU, no DS)
__device__ __forceinline__ float row16_sum(float x) {
    int t;
    t = __builtin_amdgcn_update_dpp(0, __float_as_int(x), 0x121, 0xf, 0xf, true);
    x += __int_as_float(t);
    t = __builtin_amdgcn_update_dpp(0, __float_as_int(x), 0x122, 0xf, 0xf, true);
    x += __int_as_float(t);
    t = __builtin_amdgcn_update_dpp(0, __float_as_int(x), 0x124, 0xf, 0xf, true);
    x += __int_as_float(t);
    t = __builtin_amdgcn_update_dpp(0, __float_as_int(x), 0x128, 0xf, 0xf, true);
    x += __int_as_float(t);
    return x;
}

// ---------------- weight precompute body (runs in 3 trailing blocks of k_bsw) ----------------
__device__ __forceinline__ void wall_body(
    int blk, int tid,
    const float* __restrict__ Wl, const float* __restrict__ Wr,
    const float* __restrict__ g, const float* __restrict__ be,
    const float* __restrict__ pw, const float* __restrict__ pb,
    unsigned short* __restrict__ aT0, unsigned short* __restrict__ aT1,
    unsigned short* __restrict__ fT,
    float* __restrict__ S0, float* __restrict__ C0,
    float* __restrict__ S1, float* __restrict__ C1, float* __restrict__ Cf)
{
    if (blk < 2) {
        if (tid >= 128) return;
        const int c = tid;
        const float* WL = Wl + blk * DD * DD;
        const float* WR = Wr + blk * DD * DD;
        const float* gg = g + blk * DD;
        const float* bb = be + blk * DD;
        unsigned short* aT = blk ? aT1 : aT0;
        float* S = blk ? S1 : S0;
        float* C = blk ? C1 : C0;
        const float* W = (c < 64) ? WL : WR;
        const int cc = c & 63;
        float s = 0.f, cC = 0.f;
        unsigned short* hi_p = aT + c * 64;
        unsigned short* lo_p = aT + 128 * 64 + c * 64;
        #pragma unroll 8
        for (int k = 0; k < 64; ++k) {
            float w = W[k * 64 + cc];
            float a = gg[k] * w;
            unsigned short hi = f2bf(a);
            unsigned short lo = f2bf(a - bf2f(hi));
            hi_p[k] = hi; lo_p[k] = lo;
            s += a;
            cC = fmaf(bb[k], w, cC);
        }
        S[c] = s; C[c] = cC;
    } else {
        if (tid >= 64) return;
        const int c = tid;
        unsigned short* hi_p = fT + c * 64;
        unsigned short* lo_p = fT + 64 * 64 + c * 64;
        #pragma unroll 8
        for (int k = 0; k < 64; ++k) {
            float w = pw[k * 64 + c];
            unsigned short hi = f2bf(w);
            unsigned short lo = f2bf(w - bf2f(hi));
            hi_p[k] = hi; lo_p[k] = lo;
        }
        Cf[c] = pb[c];
    }
}

// ---------------- fused: bucket scatter (blocks < SCB) || weight precompute (3 blocks) ----------------
__global__ __launch_bounds__(256) void k_bsw(
    const int* __restrict__ src, const int* __restrict__ tgt,
    int* __restrict__ bkcnt, unsigned int* __restrict__ ebuf,
    const float* __restrict__ Wl, const float* __restrict__ Wr,
    const float* __restrict__ g, const float* __restrict__ be,
    const float* __restrict__ pw, const float* __restrict__ pb,
    unsigned short* __restrict__ aT0, unsigned short* __restrict__ aT1,
    unsigned short* __restrict__ fT,
    float* __restrict__ S0, float* __restrict__ C0,
    float* __restrict__ S1, float* __restrict__ C1, float* __restrict__ Cf)
{
    __shared__ int stgt[SCH];
    __shared__ unsigned short srk[SCH];
    __shared__ int hist[NB];
    __shared__ int hbase[NB];
    if (blockIdx.x >= SCB) {
        wall_body(blockIdx.x - SCB, threadIdx.x, Wl, Wr, g, be, pw, pb,
                  aT0, aT1, fT, S0, C0, S1, C1, Cf);
        return;
    }
    const int base = blockIdx.x * SCH;
    const int cnt = min(SCH, NE - base);
    const int tid = threadIdx.x;
    for (int i = tid; i < NB; i += 256) hist[i] = 0;
    for (int i = tid; i < cnt; i += 256) stgt[i] = tgt[base + i];
    __syncthreads();
    for (int i = tid; i < cnt; i += 256)
        srk[i] = (unsigned short)atomicAdd(&hist[stgt[i] >> 8], 1);
    __syncthreads();
    for (int b = tid; b < NB; b += 256) {
        int c = hist[b];
        hbase[b] = c ? (b * BCAP + atomicAdd(&bkcnt[b], c)) : 0;
    }
    __syncthreads();
    for (int i = tid; i < cnt; i += 256) {
        int t = stgt[i];
        unsigned int e = ((unsigned int)src[base + i] << 8) | (unsigned int)(t & 255);
        ebuf[hbase[t >> 8] + (int)srk[i]] = e;
    }
}

// ---------------- MFMA node GEMM tile (device body) ----------------
template<int CTW, bool LN>
__device__ __forceinline__ void gemm_tile(
    const int tile, unsigned short* hbh, unsigned short* hbl,
    float* smean, float* srho,
    const float* __restrict__ h, const unsigned short* __restrict__ aT,
    const float* __restrict__ S, const float* __restrict__ C,
    unsigned short* __restrict__ xlb, unsigned short* __restrict__ xrb,
    float* __restrict__ outp)
{
    const int tid = threadIdx.x;
    {
        const int row = tid >> 2, q = tid & 3;
        const int node = min(tile + row, NN - 1);
        const float* hp = h + (size_t)node * DD + q * 16;
        float4 v[4];
        #pragma unroll
        for (int i = 0; i < 4; ++i) v[i] = *(const float4*)(hp + i * 4);
        if (LN) {
            float sum = 0.f, ssq = 0.f;
            #pragma unroll
            for (int i = 0; i < 4; ++i) {
                sum += v[i].x + v[i].y + v[i].z + v[i].w;
                ssq += v[i].x * v[i].x + v[i].y * v[i].y + v[i].z * v[i].z + v[i].w * v[i].w;
            }
            sum += __shfl_xor(sum, 1, 64); ssq += __shfl_xor(ssq, 1, 64);
            sum += __shfl_xor(sum, 2, 64); ssq += __shfl_xor(ssq, 2, 64);
            if (q == 0) {
                float mean = sum * 0.015625f;
                float var = ssq * 0.015625f - mean * mean;
                smean[row] = mean;
                srho[row] = rsqrtf(var + 1e-5f);
            }
        }
        #pragma unroll
        for (int half = 0; half < 2; ++half) {
            bf16x8 ph, pl;
            #pragma unroll
            for (int e = 0; e < 8; ++e) {
                float f = (&v[half * 2 + (e >> 2)].x)[e & 3];
                unsigned short hi = f2bf(f);
                unsigned short lo = f2bf(f - bf2f(hi));
                ph[e] = (short)hi; pl[e] = (short)lo;
            }
            const int so = row * HS + q * 16 + half * 8;
            *(bf16x8*)&hbh[so] = ph;
            *(bf16x8*)&hbl[so] = pl;
        }
    }
    __syncthreads();
    const int lane = tid & 63;
    const int wslot = tid >> 6;
    const int li16 = lane & 15;
    const int g16 = lane >> 4;
    const int NCT = CTW * 4;
    f32x4 acc[CTW][4];
    #pragma unroll
    for (int c = 0; c < CTW; ++c)
        #pragma unroll
        for (int rt = 0; rt < 4; ++rt) acc[c][rt] = (f32x4){0.f, 0.f, 0.f, 0.f};
    #pragma unroll
    for (int kk = 0; kk < 2; ++kk) {
        bf16x8 ah[4], al[4];
        #pragma unroll
        for (int rt = 0; rt < 4; ++rt) {
            const int so = (rt * 16 + li16) * HS + kk * 32 + g16 * 8;
            ah[rt] = *(const bf16x8*)&hbh[so];
            al[rt] = *(const bf16x8*)&hbl[so];
        }
        #pragma unroll
        for (int c = 0; c < CTW; ++c) {
            const int ct = wslot + c * 4;
            const unsigned short* bp = aT + (ct * 16 + li16) * 64 + kk * 32 + g16 * 8;
            bf16x8 bh = *(const bf16x8*)bp;
            bf16x8 bl = *(const bf16x8*)(bp + NCT * 16 * 64);
            #pragma unroll
            for (int rt = 0; rt < 4; ++rt) {
                acc[c][rt] = __builtin_amdgcn_mfma_f32_16x16x32_bf16(ah[rt], bh, acc[c][rt], 0, 0, 0);
                acc[c][rt] = __builtin_amdgcn_mfma_f32_16x16x32_bf16(al[rt], bh, acc[c][rt], 0, 0, 0);
                acc[c][rt] = __builtin_amdgcn_mfma_f32_16x16x32_bf16(ah[rt], bl, acc[c][rt], 0, 0, 0);
            }
        }
    }
    #pragma unroll
    for (int c = 0; c < CTW; ++c) {
        const int ct = wslot + c * 4;
        const int col = ct * 16 + li16;
        const float Cc = C[col];
        float Sc = 0.f;
        if (LN) Sc = S[col];
        #pragma unroll
        for (int rt = 0; rt < 4; ++rt) {
            const int r0 = rt * 16 + g16 * 4;
            #pragma unroll
            for (int j = 0; j < 4; ++j) {
                const int row2 = r0 + j;
                const int node = tile + row2;
                if (node < NN) {
                    float p = acc[c][rt][j];
                    if (LN) {
                        float val = fmaf(srho[row2], p - smean[row2] * Sc, Cc);
                        unsigned short* xb = (ct < 4) ? xlb : xrb;
                        xb[(size_t)node * DD + (col & 63)] = f2bf(val);
                    } else {
                        outp[(size_t)node * DD + col] = p + Cc;
                    }
                }
            }
        }
    }
}

template<int CTW, bool LN>
__global__ __launch_bounds__(256) void k_gemm(
    const float* __restrict__ h, const unsigned short* __restrict__ aT,
    const float* __restrict__ S, const float* __restrict__ C,
    unsigned short* __restrict__ xlb, unsigned short* __restrict__ xrb,
    float* __restrict__ outp)
{
    __shared__ __align__(16) unsigned short hbh[64 * HS];
    __shared__ __align__(16) unsigned short hbl[64 * HS];
    __shared__ float smean[64], srho[64];
    gemm_tile<CTW, LN>(blockIdx.x * 64, hbh, hbl, smean, srho,
                       h, aT, S, C, xlb, xrb, outp);
}

// ---------------- fused: bucket-finalize (blocks < NB) || layer-0 GEMM (rest) ----------------
__global__ __launch_bounds__(256) void k_bfg(
    const int* __restrict__ bkcnt, const unsigned int* __restrict__ ebuf,
    int2* __restrict__ rowse, int* __restrict__ csr,
    const float* __restrict__ h, const unsigned short* __restrict__ aT,
    const float* __restrict__ S, const float* __restrict__ C,
    unsigned short* __restrict__ xlb, unsigned short* __restrict__ xrb)
{
    __shared__ __align__(16) unsigned short hbh[64 * HS];
    __shared__ __align__(16) unsigned short hbl[64 * HS];
    __shared__ float smean[64], srho[64];
    __shared__ int hist[256];
    __shared__ int pos[256];
    __shared__ int wsum[4];
    if (blockIdx.x < NB) {
        const int b = blockIdx.x, tid = threadIdx.x;
        const int bb = b * BCAP;
        const int be = bb + bkcnt[b];
        hist[tid] = 0;
        __syncthreads();
        for (int i = bb + tid; i < be; i += 256) atomicAdd(&hist[ebuf[i] & 255u], 1);
        __syncthreads();
        const int v = hist[tid];
        const int lane = tid & 63, w = tid >> 6;
        int sc = v;
        #pragma unroll
        for (int o = 1; o < 64; o <<= 1) { int t = __shfl_up(sc, o, 64); if (lane >= o) sc += t; }
        if (lane == 63) wsum[w] = sc;
        __syncthreads();
        int off = 0;
        for (int k = 0; k < w; ++k) off += wsum[k];
        const int node = b * 256 + tid;
        const int rp = b * CCAP + off + sc - v + tid;   // +tid: self slots of preceding nodes
        if (node < NN) {
            rowse[node] = make_int2(rp, rp + 1 + v);    // [beg, end): self + deg edges
            csr[rp] = node << 6;                        // self-loop first (pre-scaled by DD)
        }
        pos[tid] = rp + 1;
        __syncthreads();
        for (int i = bb + tid; i < be; i += 256) {
            unsigned int e = ebuf[i];
            int p = atomicAdd(&pos[e & 255u], 1);
            csr[p] = (int)(e >> 8) << 6;                // pre-scaled by DD
        }
    } else {
        gemm_tile<2, true>((blockIdx.x - NB) * 64, hbh, hbl, smean, srho,
                           h, aT, S, C, xlb, xrb, nullptr);
    }
}

// ---------------- aggregation: one wave per target node, 16 lanes x 4 edges ----------------
// bf16 gathers, 2-deep clamped pipeline, DPP reduce, packed math, distributed epilogue.
__global__ __launch_bounds__(256) void k_agg(
    const int2* __restrict__ rowse, const int* __restrict__ csr,
    const unsigned short* __restrict__ xlb, const unsigned short* __restrict__ xrb,
    const float* __restrict__ att, const float* __restrict__ cbias,
    const float* __restrict__ h_in, float* __restrict__ h_out)
{
    const int lane = threadIdx.x & 63;
    const int li   = lane & 15;     // feature-quad index
    const int sub  = lane >> 4;     // edge slot 0..3
    const int li4  = li * 4;
    const int fidx = li4 + sub;     // feature this lane owns in the epilogue
    const int wid  = (blockIdx.x * 256 + threadIdx.x) >> 6;
    const int nw   = gridDim.x * 4;
    const float L2E = 1.4426950408889634f;
    const float4 ar = *(const float4*)&att[li4];
    const f32x2 a1_01  = {L2E * ar.x, L2E * ar.y};
    const f32x2 a1_23  = {L2E * ar.z, L2E * ar.w};
    const f32x2 a02_01 = {0.2f * L2E * ar.x, 0.2f * L2E * ar.y};
    const f32x2 a02_23 = {0.2f * L2E * ar.z, 0.2f * L2E * ar.w};
    const float cb = cbias[fidx];
    const f32x2 z2 = {0.f, 0.f};
    for (int n = wid; n < NN; n += nw) {
        const uint2 xru = *(const uint2*)&xrb[(size_t)n * DD + li4];
        f32x2 xrt01, xrt23;
        xrt01.x = __uint_as_float(xru.x << 16);
        xrt01.y = __uint_as_float(xru.x & 0xFFFF0000u);
        xrt23.x = __uint_as_float(xru.y << 16);
        xrt23.y = __uint_as_float(xru.y & 0xFFFF0000u);
        const int2 se = rowse[n];
        const int beg = se.x, end = se.y;                 // len >= 1 (self first)
        const int end1 = end - 1;
        // 2-deep clamped software pipeline on the bf16 gather (csr pre-scaled by 64)
        int j  = beg + sub;
        int jn = j + 4;
        uint2 v  = *(const uint2*)&xlb[(unsigned)csr[min(j,  end1)] + li4];
        uint2 vn = *(const uint2*)&xlb[(unsigned)csr[min(jn, end1)] + li4];
        float den = 0.f;
        f32x2 acc01 = z2, acc23 = z2;
        const int nch = (end - beg + 3) >> 2;
        for (int c = 0; c < nch; ++c) {
            const uint2 cur = v;
            const int jcur = j;
            v = vn;
            j = jn;
            jn += 4;
            vn = *(const uint2*)&xlb[(unsigned)csr[min(jn, end1)] + li4];  // prefetch c+2
            f32x2 f01, f23;
            f01.x = __uint_as_float(cur.x << 16);
            f01.y = __uint_as_float(cur.x & 0xFFFF0000u);
            f23.x = __uint_as_float(cur.y << 16);
            f23.y = __uint_as_float(cur.y & 0xFFFF0000u);
            const f32x2 t01 = f01 + xrt01;
            const f32x2 t23 = f23 + xrt23;
            f32x2 pv = __builtin_elementwise_max(t01, z2) * a1_01;
            pv = __builtin_elementwise_min(t01, z2) * a02_01 + pv;
            pv = __builtin_elementwise_max(t23, z2) * a1_23 + pv;
            pv = __builtin_elementwise_min(t23, z2) * a02_23 + pv;
            float p = row16_sum(pv.x + pv.y);
            float ex = (jcur < end) ? EXP2(p) : 0.f;
            den += ex;
            const f32x2 ex2 = {ex, ex};
            acc01 = f01 * ex2 + acc01;
            acc23 = f23 * ex2 + acc23;
        }
        // full butterfly across the 4 edge slots: all lanes get totals
        #pragma unroll
        for (int o = 16; o < 64; o <<= 1) {
            acc01.x += __shfl_xor(acc01.x, o, 64);
            acc01.y += __shfl_xor(acc01.y, o, 64);
            acc23.x += __shfl_xor(acc23.x, o, 64);
            acc23.y += __shfl_xor(acc23.y, o, 64);
            den     += __shfl_xor(den,     o, 64);
        }
        // distributed epilogue: each lane finishes ONE feature
        const float id = 1.f / (den + 1e-16f);
        const float v01 = (sub & 1) ? acc01.y : acc01.x;
        const float v23 = (sub & 1) ? acc23.y : acc23.x;
        const float val = (sub & 2) ? v23 : v01;
        const float o = gelu_exact(fmaf(val, id, cb)) + h_in[(size_t)n * DD + fidx];
        h_out[(size_t)n * DD + fidx] = o;
    }
}

extern "C" void kernel_launch(void* const* d_in, const int* in_sizes, int n_in,
                              void* d_out, int out_size, void* d_ws, size_t ws_size,
                              hipStream_t stream) {
    const int*   edge_index = (const int*)d_in[1];
    const int*   src   = edge_index;
    const int*   tgt   = edge_index + NE;
    const float* emb   = (const float*)d_in[2];
    const float* ln_g  = (const float*)d_in[3];
    const float* ln_b  = (const float*)d_in[4];
    const float* Wl    = (const float*)d_in[5];
    const float* Wr    = (const float*)d_in[6];
    const float* att   = (const float*)d_in[7];
    const float* cbias = (const float*)d_in[8];
    const float* pw    = (const float*)d_in[9];
    const float* pb    = (const float*)d_in[10];
    float* out = (float*)d_out;

    unsigned short* xlb = (unsigned short*)d_ws;             // NN*64 bf16
    unsigned short* xrb = xlb + (size_t)NN * DD;             // NN*64 bf16
    int* csr            = (int*)(xrb + (size_t)NN * DD);     // NB*CCAP
    unsigned int* ebuf  = (unsigned int*)(csr + NB * CCAP);  // NB*BCAP
    int2* rowse         = (int2*)(ebuf + (size_t)NB * BCAP); // NN int2
    int* bkcnt          = (int*)(rowse + NN);                // 400 (padded)
    unsigned short* aT0 = (unsigned short*)(bkcnt + 400);    // 2*128*64
    unsigned short* aT1 = aT0 + 2 * 128 * 64;
    unsigned short* fT  = aT1 + 2 * 128 * 64;                // 2*64*64
    float* S0 = (float*)(fT + 2 * 64 * 64);
    float* C0 = S0 + 128;
    float* S1 = C0 + 128;
    float* C1 = S1 + 128;
    float* Cf = C1 + 128;

    const int AGG_BLOCKS = 2048;

    // D0: zero bucket counters (DMA, no kernel)
    hipMemsetAsync(bkcnt, 0, NB * sizeof(int), stream);

    // D1: bucket scatter || weight precompute (fused)
    k_bsw<<<SCB + 3, 256, 0, stream>>>(src, tgt, bkcnt, ebuf,
                                       Wl, Wr, ln_g, ln_b, pw, pb,
                                       aT0, aT1, fT, S0, C0, S1, C1, Cf);

    // D2: bucket finalize (CSR+rowse) || layer-0 GEMM, fused
    k_bfg<<<NB + GB, 256, 0, stream>>>(bkcnt, ebuf, rowse, csr,
                                       emb, aT0, S0, C0, xlb, xrb);

    // D3: layer-0 aggregation -> h1 (out)
    k_agg<<<AGG_BLOCKS, 256, 0, stream>>>(rowse, csr, xlb, xrb, att, cbias, emb, out);

    // D4: layer-1 GEMM (h1 -> xlb, xrb)
    k_gemm<2, true><<<GB, 256, 0, stream>>>(out, aT1, S1, C1, xlb, xrb, nullptr);

    // D5: layer-1 aggregation -> h2 (out)
    k_agg<<<AGG_BLOCKS, 256, 0, stream>>>(rowse, csr, xlb, xrb, att + DD, cbias + DD, out, out);

    // D6: final projection (MFMA, in-place per row tile)
    k_gemm<1, false><<<GB, 256, 0, stream>>>(out, fT, nullptr, Cf, nullptr, nullptr, out);
}